// Round 4
// 1075.316 us; speedup vs baseline: 1.0938x; 1.0938x over previous
//
#include <hip/hip_runtime.h>
#include <math.h>

#define B 2048
#define T 512
#define D 178
#define H 5
#define G 20   // 4*H

// ------------------------------------------------------------------
// Kernel 1: input projection -> xg[t][r][b][k]
//   r = gate type 0..3 (i,f,g,o), k = element 0..4; PyTorch row g = 5r+k
//   xg[t][r][b][k] = (b_ih[g]+b_hh[g]) + sum_d x[b,t,d] * w_ih[g,d]
//
// v2: wave-uniform gate-group. Block = 64 rows (fixed t, 64 b's) staged
// once in LDS. Wave w (= gate type r) computes its 5 gates for all 64
// rows, lane = row. All w_ih accesses are wave-uniform -> scalar loads
// (SGPR operands in the FMAs), zero LDS traffic for weights.
// LDS reads: 1056 -> 176 b128 per tile; LDS 45 KB -> 3 blocks/CU.
// ------------------------------------------------------------------
#define TILE 64
#define XS_STRIDE 180   // 16B-aligned rows; quad index (45*row+i)%8 -> perfect spread

__global__ __launch_bounds__(256) void proj_kernel(
    const float* __restrict__ x, const float* __restrict__ w_ih,
    const float* __restrict__ b_ih, const float* __restrict__ b_hh,
    float* __restrict__ xg)
{
    __shared__ __align__(16) float xs[TILE * XS_STRIDE];   // 45 KB

    const int tid = threadIdx.x;
    const int rt0 = blockIdx.x * TILE;
    const int t   = rt0 >> 11;        // rt0 / B   (B = 2048)
    const int b0  = rt0 & (B - 1);    // 64-aligned, tile never crosses t

    // stage 64 x-rows: each wave stages 16 rows, 4 lanes per row along d
    {
        const int lane = tid & 63;
        const int q    = tid >> 6;
        const int row  = q * 16 + (lane >> 2);
        const int dg   = lane & 3;
        const float* xrow = x + ((size_t)(b0 + row) * T + t) * D;
        float* xsr = &xs[row * XS_STRIDE];
        #pragma unroll
        for (int i = 0; i < 23; ++i) {
            int d = dg * 2 + i * 8;          // all even d in [0,184)
            if (d < D) {
                float2 v = *(const float2*)(xrow + d);   // rows are 8B-aligned
                xsr[d]     = v.x;
                xsr[d + 1] = v.y;
            }
        }
    }
    __syncthreads();

    const int lane = tid & 63;                                   // = row
    const int r    = __builtin_amdgcn_readfirstlane(tid >> 6);   // gate type, SGPR
    const float* wb = w_ih + (size_t)r * 5 * D;

    float acc[5];
    #pragma unroll
    for (int k = 0; k < 5; ++k)
        acc[k] = b_ih[r * 5 + k] + b_hh[r * 5 + k];   // uniform -> scalar loads

    const float* xr = &xs[lane * XS_STRIDE];
    #pragma unroll 4
    for (int i = 0; i < 44; ++i) {                    // d = 0..175
        float4 xv = *(const float4*)(xr + 4 * i);
        #pragma unroll
        for (int k = 0; k < 5; ++k) {
            const float* wp = wb + k * D + 4 * i;     // wave-uniform address
            acc[k] += xv.x * wp[0] + xv.y * wp[1] + xv.z * wp[2] + xv.w * wp[3];
        }
    }
    {   // tail d = 176,177
        float2 xv = *(const float2*)(xr + 176);
        #pragma unroll
        for (int k = 0; k < 5; ++k) {
            const float* wp = wb + k * D + 176;
            acc[k] += xv.x * wp[0] + xv.y * wp[1];
        }
    }

    // xg[t][r][b][k]: scan reads this as 60 consecutive floats per instr
    float* o = xg + (((size_t)t * 4 + r) * B + (b0 + lane)) * 5;
    #pragma unroll
    for (int k = 0; k < 5; ++k) o[k] = acc[k];
}

// ------------------------------------------------------------------
// Kernel 2: sequential LSTM scan + fused FC epilogue (unchanged logic;
// only the xg indexing follows the new [t][r][b][k] layout, making the
// per-lane load offset = blockIdx*60 + lane -> fully coalesced).
// ------------------------------------------------------------------
__device__ __forceinline__ float frcp(float v) { return __builtin_amdgcn_rcpf(v); }
__device__ __forceinline__ float sigm(float v) { return frcp(1.f + __expf(-v)); }
__device__ __forceinline__ float tanh_fast(float v) {
    float e = __expf(-2.f * v);          // |v| bounded ~40 here -> no overflow
    return (1.f - e) * frcp(1.f + e);
}

#define CH 8            // prefetch chunk (steps)
#define GPB 12          // batch groups per 64-lane wave (12*5 = 60 lanes used)

__global__ __launch_bounds__(64) void scan_kernel(
    const float* __restrict__ xg, const float* __restrict__ w_hh,
    const float* __restrict__ w_fc, const float* __restrict__ b_fc,
    float* __restrict__ out)
{
    const int lane = threadIdx.x;
    int grp = lane / 5;
    int k   = lane - grp * 5;
    bool valid = (grp < GPB);
    if (!valid) { grp = 0; k = 0; }
    int b = blockIdx.x * GPB + grp;
    bool active = valid && (b < B);
    int bb = active ? b : 0;

    // per-lane weights: w_hh rows k, k+5, k+10, k+15 (i,f,g,o of element k)
    float whh[4][5];
    #pragma unroll
    for (int rr = 0; rr < 4; ++rr)
        #pragma unroll
        for (int jj = 0; jj < 5; ++jj)
            whh[rr][jj] = w_hh[(k + 5 * rr) * H + jj];
    float wfc[5];
    #pragma unroll
    for (int jj = 0; jj < 5; ++jj) wfc[jj] = w_fc[k * H + jj];
    const float bfc = b_fc[k];

    float h[5] = {0.f, 0.f, 0.f, 0.f, 0.f};
    float c = 0.f;
    const int srcbase = grp * 5;

    // xg[t][r][b][k]: addr = ((t*4 + r)*B + b)*5 + k
    const float* gb = xg + (size_t)bb * 5 + k;
    const size_t TS = (size_t)4 * B * 5;   // t stride
    const size_t RS = (size_t)B * 5;       // r stride

    float cur[CH][4], nxt[CH][4];
    #pragma unroll
    for (int s = 0; s < CH; ++s)
        #pragma unroll
        for (int rr = 0; rr < 4; ++rr)
            cur[s][rr] = gb[(size_t)s * TS + (size_t)rr * RS];

    for (int ch = 0; ch < T / CH; ++ch) {
        if (ch + 1 < T / CH) {
            const float* nb = gb + (size_t)(ch + 1) * CH * TS;
            #pragma unroll
            for (int s = 0; s < CH; ++s)
                #pragma unroll
                for (int rr = 0; rr < 4; ++rr)
                    nxt[s][rr] = nb[(size_t)s * TS + (size_t)rr * RS];
        }
        #pragma unroll
        for (int s = 0; s < CH; ++s) {
            float gi_ = cur[s][0], gf_ = cur[s][1], gg_ = cur[s][2], go_ = cur[s][3];
            #pragma unroll
            for (int jj = 0; jj < 5; ++jj) {
                gi_ += whh[0][jj] * h[jj];
                gf_ += whh[1][jj] * h[jj];
                gg_ += whh[2][jj] * h[jj];
                go_ += whh[3][jj] * h[jj];
            }
            float iv = sigm(gi_);
            float fv = sigm(gf_);
            float ov = sigm(go_);
            float gv = tanh_fast(gg_);
            c = fv * c + iv * gv;
            float hk = ov * tanh_fast(c);
            // broadcast the group's 5 new h values to all 5 lanes
            #pragma unroll
            for (int jj = 0; jj < 5; ++jj)
                h[jj] = __shfl(hk, srcbase + jj, 64);
        }
        #pragma unroll
        for (int s = 0; s < CH; ++s)
            #pragma unroll
            for (int rr = 0; rr < 4; ++rr)
                cur[s][rr] = nxt[s][rr];
    }

    // fused FC: out[b][k] = b_fc[k] + sum_j relu(h[j]) * w_fc[k][j]
    float o = bfc;
    #pragma unroll
    for (int jj = 0; jj < 5; ++jj)
        o += fmaxf(h[jj], 0.f) * wfc[jj];
    if (active) out[(size_t)b * H + k] = o;
}

// ------------------------------------------------------------------
extern "C" void kernel_launch(void* const* d_in, const int* in_sizes, int n_in,
                              void* d_out, int out_size, void* d_ws, size_t ws_size,
                              hipStream_t stream)
{
    const float* x    = (const float*)d_in[0];
    const float* w_ih = (const float*)d_in[1];
    const float* w_hh = (const float*)d_in[2];
    const float* b_ih = (const float*)d_in[3];
    const float* b_hh = (const float*)d_in[4];
    const float* w_fc = (const float*)d_in[5];
    const float* b_fc = (const float*)d_in[6];
    float* out = (float*)d_out;
    float* xg  = (float*)d_ws;   // T*4*B*5*4 = 80 MiB of workspace

    proj_kernel<<<(B * T) / TILE, 256, 0, stream>>>(x, w_ih, b_ih, b_hh, xg);
    scan_kernel<<<(B + GPB - 1) / GPB, 64, 0, stream>>>(xg, w_hh, w_fc, b_fc, out);
}